// Round 1
// baseline (77.457 us; speedup 1.0000x reference)
//
#include <hip/hip_runtime.h>

// Problem constants
#define NIMG 32
#define PIMG (512 * 512)            // 262144 pixels per image
#define BINS 4096                   // histogram bins over e in [0, 8)
#define BPI 16                      // blocks per image (kernel 1)
#define K1_THREADS 256
#define CHUNK (PIMG / BPI)          // 16384 elements per block
#define PER_T (CHUNK / K1_THREADS)  // 64 elements per thread (16 float4)
#define K2_THREADS 256
#define BINS_PER_T (BINS / K2_THREADS)  // 16

__device__ __forceinline__ float sigmoidf_(float x) {
    return 1.0f / (1.0f + __expf(-x));
}

// Workspace layout (bytes):
//   gcq  : u64 [NIMG*BINS]  (count<<32 | q)        @ 0        size 1,048,576
//   gsum : f32 [NIMG*BINS]  (sum of relu(e))       @ 1,048,576 size 524,288
//   gtp  : f32 [NIMG]                              @ 1,572,864
//   gS   : f32 [NIMG]                              @ 1,572,992
//   gp   : u32 [NIMG]                              @ 1,573,120
//   per_img: f32 [2*NIMG] (ft then lov)            @ 1,573,248
#define OFF_GSUM  (NIMG * BINS * 8)              // 1048576
#define OFF_GTP   (OFF_GSUM + NIMG * BINS * 4)   // 1572864
#define OFF_GS    (OFF_GTP + 128)
#define OFF_GP    (OFF_GS + 128)
#define OFF_PIMGR (OFF_GP + 128)
#define WS_ZERO_BYTES (OFF_GP + 128)             // zero through gp

__global__ __launch_bounds__(K1_THREADS) void k1_hist(
    const float* __restrict__ logits, const int* __restrict__ targets,
    unsigned long long* __restrict__ gcq, float* __restrict__ gsum,
    float* __restrict__ gtp, float* __restrict__ gS,
    unsigned* __restrict__ gp) {
    __shared__ unsigned hcq[BINS];   // (count<<16)|q, per-block counts <= 16384 so fields fit
    __shared__ float hsum[BINS];
    __shared__ float rtp[K1_THREADS];
    __shared__ float rS[K1_THREADS];
    __shared__ unsigned rp[K1_THREADS];

    const int tid = threadIdx.x;
    const int img = blockIdx.x / BPI;
    const int blk = blockIdx.x % BPI;

    for (int i = tid; i < BINS; i += K1_THREADS) { hcq[i] = 0u; hsum[i] = 0.0f; }
    __syncthreads();

    const long long base = (long long)img * PIMG + (long long)blk * CHUNK;
    const float4* lg4 = reinterpret_cast<const float4*>(logits + base);
    const int4* tg4 = reinterpret_cast<const int4*>(targets + base);

    float tp = 0.0f, Ssum = 0.0f;
    unsigned pc = 0;
    const float bin_scale = (float)BINS / 8.0f;

    for (int it = 0; it < PER_T / 4; ++it) {
        int idx = it * K1_THREADS + tid;
        float4 x4 = lg4[idx];
        int4 t4 = tg4[idx];
#pragma unroll
        for (int j = 0; j < 4; ++j) {
            float x = (&x4.x)[j];
            int t = (&t4.x)[j];
            float s = sigmoidf_(x);
            Ssum += s;
            float e;
            if (t) { tp += s; pc++; e = 1.0f - x; }
            else   { e = 1.0f + x; }
            if (e >= 0.0f) {
                int b = (int)(e * bin_scale);
                if (b > BINS - 1) b = BINS - 1;
                atomicAdd(&hcq[b], 0x10000u + (unsigned)(t ? 1 : 0));
                atomicAdd(&hsum[b], e);
            }
        }
    }
    __syncthreads();

    // flush histogram to global
    for (int i = tid; i < BINS; i += K1_THREADS) {
        unsigned v = hcq[i];
        if (v) {
            unsigned long long cnt = (unsigned long long)(v >> 16);
            unsigned long long q = (unsigned long long)(v & 0xffffu);
            atomicAdd(&gcq[(size_t)img * BINS + i], (cnt << 32) | q);
            atomicAdd(&gsum[(size_t)img * BINS + i], hsum[i]);
        }
    }

    // reduce tversky partials
    rtp[tid] = tp; rS[tid] = Ssum; rp[tid] = pc;
    __syncthreads();
    for (int off = K1_THREADS / 2; off > 0; off >>= 1) {
        if (tid < off) {
            rtp[tid] += rtp[tid + off];
            rS[tid] += rS[tid + off];
            rp[tid] += rp[tid + off];
        }
        __syncthreads();
    }
    if (tid == 0) {
        atomicAdd(&gtp[img], rtp[0]);
        atomicAdd(&gS[img], rS[0]);
        atomicAdd(&gp[img], rp[0]);
    }
}

__global__ __launch_bounds__(K2_THREADS) void k2_lovasz(
    const unsigned long long* __restrict__ gcq, const float* __restrict__ gsum,
    const float* __restrict__ gtp, const float* __restrict__ gS,
    const unsigned* __restrict__ gp, float* __restrict__ per_img) {
    const int img = blockIdx.x;
    const int t = threadIdx.x;
    const unsigned long long* cq = gcq + (size_t)img * BINS;
    const float* sm = gsum + (size_t)img * BINS;

    // Each thread owns BINS_PER_T bins in DESCENDING bin order:
    // d = t*BINS_PER_T + j  ->  bin = BINS-1-d
    unsigned long long own = 0ull;
#pragma unroll
    for (int j = 0; j < BINS_PER_T; ++j) {
        int bin = BINS - 1 - (t * BINS_PER_T + j);
        own += cq[bin];  // packed (cnt<<32)|q; fields can't overflow (<=262144)
    }
    __shared__ unsigned long long sc[K2_THREADS];
    sc[t] = own;
    __syncthreads();
    for (int off = 1; off < K2_THREADS; off <<= 1) {
        unsigned long long v = (t >= off) ? sc[t - off] : 0ull;
        __syncthreads();
        sc[t] += v;
        __syncthreads();
    }
    unsigned long long excl = sc[t] - own;
    long long N0 = (long long)(excl >> 32);
    long long C0 = (long long)(excl & 0xffffffffull);

    const long long p = (long long)gp[img];
    const long long n = (long long)PIMG - p;

    double lov = 0.0;
#pragma unroll 4
    for (int j = 0; j < BINS_PER_T; ++j) {
        int bin = BINS - 1 - (t * BINS_PER_T + j);
        unsigned long long v = cq[bin];
        long long g = (long long)(v >> 32);
        if (g) {
            long long q = (long long)(v & 0xffffffffull);
            double sum_a = (double)sm[bin];
            long long Ib = p - C0;            // intersection numerator before bin
            long long Ub = p + N0 - C0;       // union before bin
            long long Ia = Ib - q;
            long long Ua = Ub + g - q;
            if (n > 0) {
                double dJ;
                if (N0 == 0) {
                    // J_before defined as 0 (jaccard_diff[0] = jaccard[0])
                    dJ = 1.0 - (double)Ia / (double)Ua;
                } else {
                    // J_after - J_before = (Ib*(g-q) + q*Ub) / (Ua*Ub), cancellation-free
                    long long num = Ib * (g - q) + q * Ub;
                    dJ = (double)num / ((double)Ua * (double)Ub);
                }
                lov += (sum_a / (double)g) * dJ;
            } else {
                // n == 0: grad = jaccard (not diff); approximate with J_after
                double Jafter = 1.0 - (double)Ia / (double)Ua;
                lov += sum_a * Jafter;
            }
            N0 += g;
            C0 += q;
        }
    }

    __shared__ double rd[K2_THREADS];
    rd[t] = lov;
    __syncthreads();
    for (int off = K2_THREADS / 2; off > 0; off >>= 1) {
        if (t < off) rd[t] += rd[t + off];
        __syncthreads();
    }
    if (t == 0) {
        float tpv = gtp[img];
        float Sv = gS[img];
        float pf = (float)p;
        float fn = pf - tpv;
        float fp_ = Sv - tpv;
        float tv = (tpv + 1e-6f) / (tpv + 0.3f * fn + 0.7f * fp_ + 1e-6f);
        float bse = 1.0f - tv;
        if (bse < 0.0f) bse = 0.0f;
        per_img[img] = powf(bse, 1.33f);
        per_img[NIMG + img] = (float)rd[0];
    }
}

__global__ void k3_combine(const float* __restrict__ per_img, float* __restrict__ out) {
    if (threadIdx.x == 0 && blockIdx.x == 0) {
        float ft = 0.0f, lv = 0.0f;
        for (int i = 0; i < NIMG; ++i) {
            ft += per_img[i];
            lv += per_img[NIMG + i];
        }
        out[0] = ft / (float)NIMG + 0.2f * (lv / (float)NIMG);
    }
}

extern "C" void kernel_launch(void* const* d_in, const int* in_sizes, int n_in,
                              void* d_out, int out_size, void* d_ws, size_t ws_size,
                              hipStream_t stream) {
    const float* logits = (const float*)d_in[0];
    const int* targets = (const int*)d_in[1];
    float* out = (float*)d_out;
    char* ws = (char*)d_ws;

    unsigned long long* gcq = (unsigned long long*)ws;
    float* gsum = (float*)(ws + OFF_GSUM);
    float* gtp = (float*)(ws + OFF_GTP);
    float* gS = (float*)(ws + OFF_GS);
    unsigned* gp = (unsigned*)(ws + OFF_GP);
    float* per_img = (float*)(ws + OFF_PIMGR);

    hipMemsetAsync(d_ws, 0, WS_ZERO_BYTES, stream);
    k1_hist<<<NIMG * BPI, K1_THREADS, 0, stream>>>(logits, targets, gcq, gsum, gtp, gS, gp);
    k2_lovasz<<<NIMG, K2_THREADS, 0, stream>>>(gcq, gsum, gtp, gS, gp, per_img);
    k3_combine<<<1, 64, 0, stream>>>(per_img, out);
}

// Round 2
// 73.861 us; speedup vs baseline: 1.0487x; 1.0487x over previous
//
#include <hip/hip_runtime.h>

// Problem constants
#define NIMG 32
#define PIMG (512 * 512)            // 262144 pixels per image
#define BINS 4096                   // histogram bins over e in [0, 8)
#define BPI 64                      // blocks per image (kernel 1)
#define K1_THREADS 256
#define CHUNK (PIMG / BPI)          // 4096 elements per block
#define PER_T (CHUNK / K1_THREADS)  // 16 elements per thread (4 float4)
#define K2_THREADS 256
#define BINS_PER_T (BINS / K2_THREADS)  // 16

__device__ __forceinline__ float sigmoidf_(float x) {
    return __builtin_amdgcn_rcpf(1.0f + __expf(-x));
}

// Workspace layout (bytes):
//   gcq  : u64 [NIMG*BINS]  (count<<32 | q)        @ 0         size 1,048,576
//   gtp  : f32 [NIMG]                              @ 1,048,576
//   gS   : f32 [NIMG]                              @ +128
//   gp   : u32 [NIMG]                              @ +256
//   per_img: f32 [2*NIMG] (ft then lov)            @ +384
#define OFF_GTP   (NIMG * BINS * 8)              // 1048576
#define OFF_GS    (OFF_GTP + 128)
#define OFF_GP    (OFF_GS + 128)
#define OFF_PIMGR (OFF_GP + 128)
#define WS_ZERO_BYTES (OFF_GP + 128)             // zero through gp

__global__ __launch_bounds__(K1_THREADS) void k1_hist(
    const float* __restrict__ logits, const int* __restrict__ targets,
    unsigned long long* __restrict__ gcq,
    float* __restrict__ gtp, float* __restrict__ gS,
    unsigned* __restrict__ gp) {
    __shared__ unsigned hcq[BINS];   // (count<<16)|q; per-block count <= 4096 so fields fit
    __shared__ float redf[8];        // 4 waves x {tp, S}
    __shared__ unsigned redu[4];     // 4 waves x {p}

    const int tid = threadIdx.x;
    const int img = blockIdx.x / BPI;
    const int blk = blockIdx.x % BPI;

#pragma unroll
    for (int i = 0; i < BINS / K1_THREADS; ++i) hcq[tid + i * K1_THREADS] = 0u;
    __syncthreads();

    const long long base = (long long)img * PIMG + (long long)blk * CHUNK;
    const float4* lg4 = reinterpret_cast<const float4*>(logits + base);
    const int4* tg4 = reinterpret_cast<const int4*>(targets + base);

    // issue all global loads up front (8 loads in flight)
    float4 x4[PER_T / 4];
    int4 t4[PER_T / 4];
#pragma unroll
    for (int it = 0; it < PER_T / 4; ++it) {
        x4[it] = lg4[it * K1_THREADS + tid];
        t4[it] = tg4[it * K1_THREADS + tid];
    }

    float tp = 0.0f, Ssum = 0.0f;
    unsigned pc = 0;

#pragma unroll
    for (int it = 0; it < PER_T / 4; ++it) {
#pragma unroll
        for (int j = 0; j < 4; ++j) {
            float x = (&x4[it].x)[j];
            int t = (&t4[it].x)[j];
            float s = sigmoidf_(x);
            Ssum += s;
            float e;
            if (t) { tp += s; pc++; e = 1.0f - x; }
            else   { e = 1.0f + x; }
            if (e >= 0.0f) {
                int b = (int)(e * ((float)BINS / 8.0f));
                if (b > BINS - 1) b = BINS - 1;
                atomicAdd(&hcq[b], 0x10000u + (unsigned)(t ? 1 : 0));
            }
        }
    }
    __syncthreads();

    // flush histogram to global (skip empty bins)
#pragma unroll
    for (int i = 0; i < BINS / K1_THREADS; ++i) {
        int bin = tid + i * K1_THREADS;
        unsigned v = hcq[bin];
        if (v) {
            unsigned long long cnt = (unsigned long long)(v >> 16);
            unsigned long long q = (unsigned long long)(v & 0xffffu);
            atomicAdd(&gcq[(size_t)img * BINS + bin], (cnt << 32) | q);
        }
    }

    // wave shuffle reduction of tversky partials
    unsigned pcu = pc;
#pragma unroll
    for (int off = 32; off > 0; off >>= 1) {
        tp += __shfl_down(tp, off);
        Ssum += __shfl_down(Ssum, off);
        pcu += __shfl_down(pcu, off);
    }
    const int lane = tid & 63, w = tid >> 6;
    if (lane == 0) { redf[w * 2] = tp; redf[w * 2 + 1] = Ssum; redu[w] = pcu; }
    __syncthreads();
    if (tid == 0) {
        float tpt = redf[0] + redf[2] + redf[4] + redf[6];
        float St = redf[1] + redf[3] + redf[5] + redf[7];
        unsigned pt = redu[0] + redu[1] + redu[2] + redu[3];
        atomicAdd(&gtp[img], tpt);
        atomicAdd(&gS[img], St);
        atomicAdd(&gp[img], pt);
    }
}

__global__ __launch_bounds__(K2_THREADS) void k2_lovasz(
    const unsigned long long* __restrict__ gcq,
    const float* __restrict__ gtp, const float* __restrict__ gS,
    const unsigned* __restrict__ gp, float* __restrict__ per_img) {
    const int img = blockIdx.x;
    const int t = threadIdx.x;
    const unsigned long long* cq = gcq + (size_t)img * BINS;

    // Each thread owns BINS_PER_T bins in DESCENDING bin order:
    // d = t*BINS_PER_T + j  ->  bin = BINS-1-d
    unsigned long long own = 0ull;
#pragma unroll
    for (int j = 0; j < BINS_PER_T; ++j) {
        int bin = BINS - 1 - (t * BINS_PER_T + j);
        own += cq[bin];  // packed (cnt<<32)|q; fields can't overflow (<=262144)
    }
    __shared__ unsigned long long sc[K2_THREADS];
    sc[t] = own;
    __syncthreads();
    for (int off = 1; off < K2_THREADS; off <<= 1) {
        unsigned long long v = (t >= off) ? sc[t - off] : 0ull;
        __syncthreads();
        sc[t] += v;
        __syncthreads();
    }
    unsigned long long excl = sc[t] - own;
    long long N0 = (long long)(excl >> 32);
    long long C0 = (long long)(excl & 0xffffffffull);

    const long long p = (long long)gp[img];
    const long long n = (long long)PIMG - p;
    const double wbin = 8.0 / (double)BINS;

    double lov = 0.0;
#pragma unroll 4
    for (int j = 0; j < BINS_PER_T; ++j) {
        int bin = BINS - 1 - (t * BINS_PER_T + j);
        unsigned long long v = cq[bin];
        long long g = (long long)(v >> 32);
        if (g) {
            long long q = (long long)(v & 0xffffffffull);
            double center = ((double)bin + 0.5) * wbin;  // mean relu(e) approx
            long long Ib = p - C0;            // intersection numerator before bin
            long long Ub = p + N0 - C0;       // union before bin
            long long Ia = Ib - q;
            long long Ua = Ub + g - q;
            if (n > 0) {
                double dJ;
                if (N0 == 0) {
                    // J_before defined as 0 (jaccard_diff[0] = jaccard[0])
                    dJ = 1.0 - (double)Ia / (double)Ua;
                } else {
                    // J_after - J_before = (Ib*(g-q) + q*Ub) / (Ua*Ub), cancellation-free
                    long long num = Ib * (g - q) + q * Ub;
                    dJ = (double)num / ((double)Ua * (double)Ub);
                }
                lov += center * dJ;
            } else {
                // n == 0: grad = jaccard (not diff); approximate with J_after
                double Jafter = 1.0 - (double)Ia / (double)Ua;
                lov += (double)g * center * Jafter;
            }
            N0 += g;
            C0 += q;
        }
    }

    __shared__ double rd[K2_THREADS];
    rd[t] = lov;
    __syncthreads();
    for (int off = K2_THREADS / 2; off > 0; off >>= 1) {
        if (t < off) rd[t] += rd[t + off];
        __syncthreads();
    }
    if (t == 0) {
        float tpv = gtp[img];
        float Sv = gS[img];
        float pf = (float)p;
        float fn = pf - tpv;
        float fp_ = Sv - tpv;
        float tv = (tpv + 1e-6f) / (tpv + 0.3f * fn + 0.7f * fp_ + 1e-6f);
        float bse = 1.0f - tv;
        if (bse < 0.0f) bse = 0.0f;
        per_img[img] = powf(bse, 1.33f);
        per_img[NIMG + img] = (float)rd[0];
    }
}

__global__ void k3_combine(const float* __restrict__ per_img, float* __restrict__ out) {
    if (threadIdx.x == 0 && blockIdx.x == 0) {
        float ft = 0.0f, lv = 0.0f;
        for (int i = 0; i < NIMG; ++i) {
            ft += per_img[i];
            lv += per_img[NIMG + i];
        }
        out[0] = ft / (float)NIMG + 0.2f * (lv / (float)NIMG);
    }
}

extern "C" void kernel_launch(void* const* d_in, const int* in_sizes, int n_in,
                              void* d_out, int out_size, void* d_ws, size_t ws_size,
                              hipStream_t stream) {
    const float* logits = (const float*)d_in[0];
    const int* targets = (const int*)d_in[1];
    float* out = (float*)d_out;
    char* ws = (char*)d_ws;

    unsigned long long* gcq = (unsigned long long*)ws;
    float* gtp = (float*)(ws + OFF_GTP);
    float* gS = (float*)(ws + OFF_GS);
    unsigned* gp = (unsigned*)(ws + OFF_GP);
    float* per_img = (float*)(ws + OFF_PIMGR);

    hipMemsetAsync(d_ws, 0, WS_ZERO_BYTES, stream);
    k1_hist<<<NIMG * BPI, K1_THREADS, 0, stream>>>(logits, targets, gcq, gtp, gS, gp);
    k2_lovasz<<<NIMG, K2_THREADS, 0, stream>>>(gcq, gtp, gS, gp, per_img);
    k3_combine<<<1, 64, 0, stream>>>(per_img, out);
}

// Round 3
// 37.085 us; speedup vs baseline: 2.0886x; 1.9916x over previous
//
#include <hip/hip_runtime.h>

// Problem constants
#define NIMG 32
#define PIMG (512 * 512)             // 262144 pixels per image
#define BINS 2048                    // histogram bins over e in [0, 8)
#define BPI 32                       // blocks per image (kernel 1)
#define K1_THREADS 256
#define CHUNK (PIMG / BPI)           // 8192 elements per block
#define PER_T (CHUNK / K1_THREADS)   // 32 elements per thread (8 float4)
#define K2_THREADS 256
#define POS_PER_T (BINS / K2_THREADS) // 8 bin-positions per thread

__device__ __forceinline__ float sigmoidf_(float x) {
    return __builtin_amdgcn_rcpf(1.0f + __expf(-x));
}

// Workspace layout (bytes) — everything fully rewritten each call, no memset:
//   gpart  : u32 [NIMG*BPI][BINS]   @ 0            size 1024*2048*4 = 8 MB
//   gtv    : float4 [NIMG*BPI]      @ 8 MB         16 KB   {tp, S, p, pad}
//   per_img: f32 [2*NIMG]           @ 8 MB + 16 KB 256 B
#define OFF_GTV   (NIMG * BPI * BINS * 4)
#define OFF_PIMG  (OFF_GTV + NIMG * BPI * 16)

__global__ __launch_bounds__(K1_THREADS, 4) void k1_hist(
    const float* __restrict__ logits, const int* __restrict__ targets,
    unsigned* __restrict__ gpart, float4* __restrict__ gtv) {
    __shared__ unsigned hcq[BINS];   // (count<<16)|q; per-block count <= 8192 fits
    __shared__ float red[12];        // 4 waves x {tp, S, pc}

    const int tid = threadIdx.x;
    const int img = blockIdx.x >> 5;
    const int blk = blockIdx.x & 31;

#pragma unroll
    for (int i = 0; i < BINS / K1_THREADS; ++i) hcq[tid + i * K1_THREADS] = 0u;
    __syncthreads();

    const long long base = (long long)img * PIMG + (long long)blk * CHUNK;
    const float4* lg4 = reinterpret_cast<const float4*>(logits + base);
    const int4* tg4 = reinterpret_cast<const int4*>(targets + base);

    // issue all global loads up front (16 loads in flight)
    float4 x4[PER_T / 4];
    int4 t4[PER_T / 4];
#pragma unroll
    for (int it = 0; it < PER_T / 4; ++it) {
        x4[it] = lg4[it * K1_THREADS + tid];
        t4[it] = tg4[it * K1_THREADS + tid];
    }

    float tp = 0.0f, Ssum = 0.0f;
    unsigned pc = 0;

#pragma unroll
    for (int it = 0; it < PER_T / 4; ++it) {
#pragma unroll
        for (int j = 0; j < 4; ++j) {
            float x = (&x4[it].x)[j];
            int t = (&t4[it].x)[j];
            float s = sigmoidf_(x);
            Ssum += s;
            if (t) { tp += s; pc++; }
            float e = t ? (1.0f - x) : (1.0f + x);
            if (e >= 0.0f) {
                int b = (int)(e * ((float)BINS / 8.0f));
                if (b > BINS - 1) b = BINS - 1;
                atomicAdd(&hcq[b], 0x10000u + (unsigned)t);
            }
        }
    }
    __syncthreads();

    // flush histogram: PLAIN coalesced stores to this block's private slice
    unsigned* dst = gpart + (size_t)blockIdx.x * BINS;
#pragma unroll
    for (int i = 0; i < BINS / K1_THREADS; ++i)
        dst[tid + i * K1_THREADS] = hcq[tid + i * K1_THREADS];

    // wave shuffle reduction of tversky partials -> single float4 store
    unsigned pcu = pc;
#pragma unroll
    for (int off = 32; off > 0; off >>= 1) {
        tp += __shfl_down(tp, off);
        Ssum += __shfl_down(Ssum, off);
        pcu += __shfl_down(pcu, off);
    }
    const int lane = tid & 63, w = tid >> 6;
    if (lane == 0) { red[w * 3] = tp; red[w * 3 + 1] = Ssum; red[w * 3 + 2] = (float)pcu; }
    __syncthreads();
    if (tid == 0) {
        gtv[blockIdx.x] = make_float4(red[0] + red[3] + red[6] + red[9],
                                      red[1] + red[4] + red[7] + red[10],
                                      red[2] + red[5] + red[8] + red[11], 0.0f);
    }
}

__global__ __launch_bounds__(K2_THREADS) void k2_lovasz(
    const unsigned* __restrict__ gpart, const float4* __restrict__ gtv,
    float* __restrict__ per_img) {
    const int img = blockIdx.x;
    const int t = threadIdx.x;
    const int lane = t & 63, w = t >> 6;

    __shared__ float smx[4];
    __shared__ unsigned long long wt[8];   // double-buffered wave step-totals
    __shared__ double rd[4];

    // ---- 1) reduce tversky partials (32 per image) ----
    float4 v = make_float4(0.f, 0.f, 0.f, 0.f);
    if (t < 32) v = gtv[img * BPI + t];
#pragma unroll
    for (int off = 16; off > 0; off >>= 1) {
        v.x += __shfl_down(v.x, off);
        v.y += __shfl_down(v.y, off);
        v.z += __shfl_down(v.z, off);
    }
    if (t == 0) { smx[0] = v.x; smx[1] = v.y; smx[2] = v.z; }
    __syncthreads();
    const float tpv = smx[0], Sv = smx[1];
    const long long p = (long long)(smx[2] + 0.5f);
    const long long n = (long long)PIMG - p;

    // ---- 2) sum 32 partial hists; thread t owns bins b = j*256 + t ----
    unsigned long long own[POS_PER_T];  // packed (cnt<<32)|q per owned bin
#pragma unroll
    for (int j = 0; j < POS_PER_T; ++j) own[j] = 0ull;
    const unsigned* basep = gpart + (size_t)img * BPI * BINS;
    for (int blk = 0; blk < BPI; ++blk) {
        const unsigned* row = basep + (size_t)blk * BINS;
#pragma unroll
        for (int j = 0; j < POS_PER_T; ++j) {
            unsigned u = row[j * K2_THREADS + t];   // coalesced
            own[j] += ((unsigned long long)(u >> 16) << 32) |
                      (unsigned long long)(u & 0xffffu);
        }
    }

    // ---- 3) descending-e scan: steps j = 7..0 (bin j*256+t; larger bin = larger e) ----
    unsigned long long runHigh = 0ull;  // totals of all bins above current step
    double lov = 0.0;
    const double wbin = 8.0 / (double)BINS;

    for (int j = POS_PER_T - 1; j >= 0; --j) {
        const unsigned long long val = own[j];
        // wave inclusive suffix sum: incl[t] = sum_{t'>=t in wave} val[t']
        unsigned long long incl = val;
#pragma unroll
        for (int off = 1; off < 64; off <<= 1) {
            unsigned long long o = __shfl_down(incl, off);
            if (lane + off < 64) incl += o;
        }
        const int buf = (j & 1) * 4;
        if (lane == 0) wt[buf + w] = incl;
        __syncthreads();
        unsigned long long higher = 0ull, stepTotal = 0ull;
#pragma unroll
        for (int w2 = 0; w2 < 4; ++w2) {
            unsigned long long tw = wt[buf + w2];
            stepTotal += tw;
            if (w2 > w) higher += tw;
        }
        const unsigned long long before = runHigh + higher + (incl - val);

        const long long g = (long long)(val >> 32);
        if (g) {
            const long long q = (long long)(val & 0xffffffffull);
            const long long N0 = (long long)(before >> 32);
            const long long C0 = (long long)(before & 0xffffffffull);
            const int bin = j * K2_THREADS + t;
            const double center = ((double)bin + 0.5) * wbin;
            const long long Ib = p - C0;        // intersection before
            const long long Ub = p + N0 - C0;   // union before
            const long long Ia = Ib - q;
            const long long Ua = Ub + g - q;
            if (n > 0) {
                double dJ;
                if (N0 == 0) {
                    // sum of grads over first bin telescopes to J_after
                    dJ = 1.0 - (double)Ia / (double)Ua;
                } else {
                    // J_after - J_before = (Ib*(g-q) + q*Ub) / (Ua*Ub)
                    const long long num = Ib * (g - q) + q * Ub;
                    dJ = (double)num / ((double)Ua * (double)Ub);
                }
                lov += center * dJ;
            } else {
                const double Jafter = 1.0 - (double)Ia / (double)Ua;
                lov += (double)g * center * Jafter;
            }
        }
        runHigh += stepTotal;
    }

    // ---- 4) reduce lov across block ----
#pragma unroll
    for (int off = 32; off > 0; off >>= 1) lov += __shfl_down(lov, off);
    if (lane == 0) rd[w] = lov;
    __syncthreads();
    if (t == 0) {
        const double lovt = rd[0] + rd[1] + rd[2] + rd[3];
        const float pf = (float)p;
        const float fn = pf - tpv;
        const float fp_ = Sv - tpv;
        const float tv = (tpv + 1e-6f) / (tpv + 0.3f * fn + 0.7f * fp_ + 1e-6f);
        float bse = 1.0f - tv;
        if (bse < 0.0f) bse = 0.0f;
        per_img[img] = powf(bse, 1.33f);
        per_img[NIMG + img] = (float)lovt;
    }
}

__global__ void k3_combine(const float* __restrict__ per_img, float* __restrict__ out) {
    const int t = threadIdx.x;
    float x = 0.0f;
    if (t < NIMG) x = per_img[t] + 0.2f * per_img[NIMG + t];
#pragma unroll
    for (int off = 16; off > 0; off >>= 1) x += __shfl_down(x, off);
    if (t == 0) out[0] = x / (float)NIMG;
}

extern "C" void kernel_launch(void* const* d_in, const int* in_sizes, int n_in,
                              void* d_out, int out_size, void* d_ws, size_t ws_size,
                              hipStream_t stream) {
    const float* logits = (const float*)d_in[0];
    const int* targets = (const int*)d_in[1];
    float* out = (float*)d_out;
    char* ws = (char*)d_ws;

    unsigned* gpart = (unsigned*)ws;
    float4* gtv = (float4*)(ws + OFF_GTV);
    float* per_img = (float*)(ws + OFF_PIMG);

    k1_hist<<<NIMG * BPI, K1_THREADS, 0, stream>>>(logits, targets, gpart, gtv);
    k2_lovasz<<<NIMG, K2_THREADS, 0, stream>>>(gpart, gtv, per_img);
    k3_combine<<<1, 64, 0, stream>>>(per_img, out);
}

// Round 4
// 29.056 us; speedup vs baseline: 2.6658x; 1.2763x over previous
//
#include <hip/hip_runtime.h>

// Problem constants
#define NIMG 32
#define PIMG (512 * 512)             // 262144 pixels per image
#define BINS 2048                    // histogram bins over e in [0, 8)
#define BPI 32                       // blocks per image (kernel 1)
#define K1_THREADS 256
#define CHUNK (PIMG / BPI)           // 8192 elements per block
#define PER_T (CHUNK / K1_THREADS)   // 32 elements per thread (8 float4)
#define K2_THREADS 256
#define SLICES 8                     // k2: slices per image (256 bins each)
#define K3_THREADS 256
#define POS_PER_T (BINS / K3_THREADS) // 8 bin-positions per thread
#define FIXED_SCALE 17592186044416.0  // 2^44

__device__ __forceinline__ float sigmoidf_(float x) {
    return __builtin_amdgcn_rcpf(1.0f + __expf(-x));
}

// Workspace layout (bytes) — all live regions fully rewritten each call:
//   gpart : u32 [NIMG*BPI][BINS]    @ 0          8 MB   (cnt<<16 | q)
//   gtv   : float4 [NIMG*BPI]       @ 8 MB       16 KB  {tp, S, p, pad}
//   ghist : u64 [NIMG][BINS]        @ +16 KB     512 KB (cnt<<32 | q)
//   gacc  : u64 [2]                 @ +512 KB    {fixed-point sum, done count}
#define OFF_GTV   (NIMG * BPI * BINS * 4)
#define OFF_GHIST (OFF_GTV + NIMG * BPI * 16)
#define OFF_GACC  (OFF_GHIST + NIMG * BINS * 8)

__global__ __launch_bounds__(K1_THREADS, 4) void k1_hist(
    const float* __restrict__ logits, const int* __restrict__ targets,
    unsigned* __restrict__ gpart, float4* __restrict__ gtv,
    unsigned long long* __restrict__ gacc) {
    __shared__ unsigned hcq[BINS];   // (count<<16)|q; per-block count <= 8192 fits
    __shared__ float red[12];        // 4 waves x {tp, S, pc}

    const int tid = threadIdx.x;
    const int img = blockIdx.x >> 5;
    const int blk = blockIdx.x & 31;

    // reset the cross-call accumulator (k3 runs after k1; dispatch order guarantees visibility)
    if (blockIdx.x == 0 && tid == 0) { gacc[0] = 0ull; gacc[1] = 0ull; }

#pragma unroll
    for (int i = 0; i < BINS / K1_THREADS; ++i) hcq[tid + i * K1_THREADS] = 0u;
    __syncthreads();

    const long long base = (long long)img * PIMG + (long long)blk * CHUNK;
    const float4* lg4 = reinterpret_cast<const float4*>(logits + base);
    const int4* tg4 = reinterpret_cast<const int4*>(targets + base);

    // issue all global loads up front (16 loads in flight)
    float4 x4[PER_T / 4];
    int4 t4[PER_T / 4];
#pragma unroll
    for (int it = 0; it < PER_T / 4; ++it) {
        x4[it] = lg4[it * K1_THREADS + tid];
        t4[it] = tg4[it * K1_THREADS + tid];
    }

    float tp = 0.0f, Ssum = 0.0f;
    unsigned pc = 0;

#pragma unroll
    for (int it = 0; it < PER_T / 4; ++it) {
#pragma unroll
        for (int j = 0; j < 4; ++j) {
            float x = (&x4[it].x)[j];
            int t = (&t4[it].x)[j];
            float s = sigmoidf_(x);
            Ssum += s;
            if (t) { tp += s; pc++; }
            float e = t ? (1.0f - x) : (1.0f + x);
            if (e >= 0.0f) {
                int b = (int)(e * ((float)BINS / 8.0f));
                if (b > BINS - 1) b = BINS - 1;
                atomicAdd(&hcq[b], 0x10000u + (unsigned)t);
            }
        }
    }
    __syncthreads();

    // flush histogram: PLAIN coalesced stores to this block's private slice
    unsigned* dst = gpart + (size_t)blockIdx.x * BINS;
#pragma unroll
    for (int i = 0; i < BINS / K1_THREADS; ++i)
        dst[tid + i * K1_THREADS] = hcq[tid + i * K1_THREADS];

    // wave shuffle reduction of tversky partials -> single float4 store
    unsigned pcu = pc;
#pragma unroll
    for (int off = 32; off > 0; off >>= 1) {
        tp += __shfl_down(tp, off);
        Ssum += __shfl_down(Ssum, off);
        pcu += __shfl_down(pcu, off);
    }
    const int lane = tid & 63, w = tid >> 6;
    if (lane == 0) { red[w * 3] = tp; red[w * 3 + 1] = Ssum; red[w * 3 + 2] = (float)pcu; }
    __syncthreads();
    if (tid == 0) {
        gtv[blockIdx.x] = make_float4(red[0] + red[3] + red[6] + red[9],
                                      red[1] + red[4] + red[7] + red[10],
                                      red[2] + red[5] + red[8] + red[11], 0.0f);
    }
}

// k2: full-chip reduction of the 32 partial hists per image.
// Block (img, slice) sums gpart[img*BPI + 0..31][slice*256 + t] -> ghist.
__global__ __launch_bounds__(K2_THREADS) void k2_reduce(
    const unsigned* __restrict__ gpart, unsigned long long* __restrict__ ghist) {
    const int t = threadIdx.x;
    const int img = blockIdx.x >> 3;
    const int sl = blockIdx.x & (SLICES - 1);
    const int bin = sl * K2_THREADS + t;

    const unsigned* basep = gpart + (size_t)img * BPI * BINS + bin;
    unsigned c = 0, q = 0;
#pragma unroll
    for (int blk = 0; blk < BPI; ++blk) {
        unsigned u = basep[(size_t)blk * BINS];   // coalesced within block
        c += (u >> 16);
        q += (u & 0xffffu);
    }
    ghist[(size_t)img * BINS + bin] = ((unsigned long long)c << 32) | (unsigned long long)q;
}

// k3: per-image descending scan + tversky + deterministic fixed-point combine.
__global__ __launch_bounds__(K3_THREADS) void k3_lovasz(
    const unsigned long long* __restrict__ ghist, const float4* __restrict__ gtv,
    unsigned long long* __restrict__ gacc, float* __restrict__ out) {
    const int img = blockIdx.x;
    const int t = threadIdx.x;
    const int lane = t & 63, w = t >> 6;

    __shared__ float smx[4];
    __shared__ unsigned long long wt[8];   // double-buffered wave step-totals
    __shared__ double rd[4];

    // ---- 1) reduce tversky partials (32 per image) ----
    float4 v = make_float4(0.f, 0.f, 0.f, 0.f);
    if (t < 32) v = gtv[img * BPI + t];
#pragma unroll
    for (int off = 16; off > 0; off >>= 1) {
        v.x += __shfl_down(v.x, off);
        v.y += __shfl_down(v.y, off);
        v.z += __shfl_down(v.z, off);
    }
    if (t == 0) { smx[0] = v.x; smx[1] = v.y; smx[2] = v.z; }

    // ---- 2) load summed hist; thread t owns bins b = j*256 + t ----
    unsigned long long own[POS_PER_T];
    const unsigned long long* hb = ghist + (size_t)img * BINS;
#pragma unroll
    for (int j = 0; j < POS_PER_T; ++j) own[j] = hb[j * K3_THREADS + t];
    __syncthreads();
    const float tpv = smx[0], Sv = smx[1];
    const long long p = (long long)(smx[2] + 0.5f);
    const long long n = (long long)PIMG - p;

    // ---- 3) descending-e scan: steps j = 7..0 (bin j*256+t; larger bin = larger e) ----
    unsigned long long runHigh = 0ull;  // totals of all bins above current step
    double lov = 0.0;
    const double wbin = 8.0 / (double)BINS;

    for (int j = POS_PER_T - 1; j >= 0; --j) {
        const unsigned long long val = own[j];
        // wave inclusive suffix sum: incl[t] = sum_{t'>=t in wave} val[t']
        unsigned long long incl = val;
#pragma unroll
        for (int off = 1; off < 64; off <<= 1) {
            unsigned long long o = __shfl_down(incl, off);
            if (lane + off < 64) incl += o;
        }
        const int buf = (j & 1) * 4;
        if (lane == 0) wt[buf + w] = incl;
        __syncthreads();
        unsigned long long higher = 0ull, stepTotal = 0ull;
#pragma unroll
        for (int w2 = 0; w2 < 4; ++w2) {
            unsigned long long tw = wt[buf + w2];
            stepTotal += tw;
            if (w2 > w) higher += tw;
        }
        const unsigned long long before = runHigh + higher + (incl - val);

        const long long g = (long long)(val >> 32);
        if (g) {
            const long long q = (long long)(val & 0xffffffffull);
            const long long N0 = (long long)(before >> 32);
            const long long C0 = (long long)(before & 0xffffffffull);
            const int bin = j * K3_THREADS + t;
            const double center = ((double)bin + 0.5) * wbin;
            const long long Ib = p - C0;        // intersection before
            const long long Ub = p + N0 - C0;   // union before
            const long long Ia = Ib - q;
            const long long Ua = Ub + g - q;
            if (n > 0) {
                double dJ;
                if (N0 == 0) {
                    // sum of grads over first bin telescopes to J_after
                    dJ = 1.0 - (double)Ia / (double)Ua;
                } else {
                    // J_after - J_before = (Ib*(g-q) + q*Ub) / (Ua*Ub)
                    const long long num = Ib * (g - q) + q * Ub;
                    dJ = (double)num / ((double)Ua * (double)Ub);
                }
                lov += center * dJ;
            } else {
                const double Jafter = 1.0 - (double)Ia / (double)Ua;
                lov += (double)g * center * Jafter;
            }
        }
        runHigh += stepTotal;
    }

    // ---- 4) reduce lov across block, combine, fixed-point atomic accumulate ----
#pragma unroll
    for (int off = 32; off > 0; off >>= 1) lov += __shfl_down(lov, off);
    if (lane == 0) rd[w] = lov;
    __syncthreads();
    if (t == 0) {
        const double lovt = rd[0] + rd[1] + rd[2] + rd[3];
        const float pf = (float)p;
        const float fn = pf - tpv;
        const float fp_ = Sv - tpv;
        const float tv = (tpv + 1e-6f) / (tpv + 0.3f * fn + 0.7f * fp_ + 1e-6f);
        float bse = 1.0f - tv;
        if (bse < 0.0f) bse = 0.0f;
        const double contrib = ((double)powf(bse, 1.33f) + 0.2 * lovt) / (double)NIMG;
        const long long fx = (long long)(contrib * FIXED_SCALE);
        atomicAdd(&gacc[0], (unsigned long long)fx);
        __threadfence();
        const unsigned long long done = atomicAdd(&gacc[1], 1ull);
        if (done == (unsigned long long)(NIMG - 1)) {
            const unsigned long long sum = atomicAdd(&gacc[0], 0ull);  // coherent read
            out[0] = (float)((double)(long long)sum / FIXED_SCALE);
        }
    }
}

extern "C" void kernel_launch(void* const* d_in, const int* in_sizes, int n_in,
                              void* d_out, int out_size, void* d_ws, size_t ws_size,
                              hipStream_t stream) {
    const float* logits = (const float*)d_in[0];
    const int* targets = (const int*)d_in[1];
    float* out = (float*)d_out;
    char* ws = (char*)d_ws;

    unsigned* gpart = (unsigned*)ws;
    float4* gtv = (float4*)(ws + OFF_GTV);
    unsigned long long* ghist = (unsigned long long*)(ws + OFF_GHIST);
    unsigned long long* gacc = (unsigned long long*)(ws + OFF_GACC);

    k1_hist<<<NIMG * BPI, K1_THREADS, 0, stream>>>(logits, targets, gpart, gtv, gacc);
    k2_reduce<<<NIMG * SLICES, K2_THREADS, 0, stream>>>(gpart, ghist);
    k3_lovasz<<<NIMG, K3_THREADS, 0, stream>>>(ghist, gtv, gacc, out);
}

// Round 5
// 27.266 us; speedup vs baseline: 2.8408x; 1.0657x over previous
//
#include <hip/hip_runtime.h>

// Problem constants
#define NIMG 32
#define PIMG (512 * 512)             // 262144 pixels per image
#define BINS 1024                    // histogram bins over e in [0, 8)
#define BPI 64                       // blocks per image (kernel 1)
#define K1_THREADS 256
#define CHUNK (PIMG / BPI)           // 4096 elements per block
#define PER_T (CHUNK / K1_THREADS)   // 16 elements per thread (4 float4)
#define K2_THREADS 128
#define SLICES 8                     // k2: slices per image (128 bins each)
#define K3_THREADS 256
#define POS_PER_T (BINS / K3_THREADS) // 4 bin-positions per thread
#define FIXED_SCALE 17592186044416.0  // 2^44

__device__ __forceinline__ float sigmoidf_(float x) {
    return __builtin_amdgcn_rcpf(1.0f + __expf(-x));
}

// Workspace layout (bytes) — all live regions fully rewritten each call:
//   gpart : u32 [NIMG*BPI][BINS]    @ 0          8 MB   (cnt<<16 | q)
//   gtv   : float4 [NIMG*BPI]       @ 8 MB       32 KB  {tp, S, p, pad}
//   ghist : u64 [NIMG][BINS]        @ +32 KB     256 KB (cnt<<32 | q)
//   gacc  : u64 [2]                 @ +256 KB    {fixed-point sum, done count}
#define OFF_GTV   (NIMG * BPI * BINS * 4)
#define OFF_GHIST (OFF_GTV + NIMG * BPI * 16)
#define OFF_GACC  (OFF_GHIST + NIMG * BINS * 8)

__global__ __launch_bounds__(K1_THREADS, 8) void k1_hist(
    const float* __restrict__ logits, const int* __restrict__ targets,
    unsigned* __restrict__ gpart, float4* __restrict__ gtv,
    unsigned long long* __restrict__ gacc) {
    __shared__ unsigned hcq[BINS];   // (count<<16)|q; per-block count <= 4096 fits
    __shared__ float red[12];        // 4 waves x {tp, S, pc}

    const int tid = threadIdx.x;
    const int img = blockIdx.x >> 6;
    const int blk = blockIdx.x & 63;

    // reset the cross-kernel accumulator (k3 runs after k1 on the same stream)
    if (blockIdx.x == 0 && tid == 0) { gacc[0] = 0ull; gacc[1] = 0ull; }

#pragma unroll
    for (int i = 0; i < BINS / K1_THREADS; ++i) hcq[tid + i * K1_THREADS] = 0u;
    __syncthreads();

    const long long base = (long long)img * PIMG + (long long)blk * CHUNK;
    const float4* lg4 = reinterpret_cast<const float4*>(logits + base);
    const int4* tg4 = reinterpret_cast<const int4*>(targets + base);

    // issue all global loads up front (8 loads in flight)
    float4 x4[PER_T / 4];
    int4 t4[PER_T / 4];
#pragma unroll
    for (int it = 0; it < PER_T / 4; ++it) {
        x4[it] = lg4[it * K1_THREADS + tid];
        t4[it] = tg4[it * K1_THREADS + tid];
    }

    float tp = 0.0f, Ssum = 0.0f;
    unsigned pc = 0;

#pragma unroll
    for (int it = 0; it < PER_T / 4; ++it) {
#pragma unroll
        for (int j = 0; j < 4; ++j) {
            float x = (&x4[it].x)[j];
            int t = (&t4[it].x)[j];
            float s = sigmoidf_(x);
            Ssum += s;
            if (t) { tp += s; pc++; }
            float e = t ? (1.0f - x) : (1.0f + x);
            if (e >= 0.0f) {
                int b = (int)(e * ((float)BINS / 8.0f));
                if (b > BINS - 1) b = BINS - 1;
                atomicAdd(&hcq[b], 0x10000u + (unsigned)t);
            }
        }
    }
    __syncthreads();

    // flush histogram: one uint4 per thread, plain coalesced 16B stores
    uint4* dst = reinterpret_cast<uint4*>(gpart + (size_t)blockIdx.x * BINS);
    dst[tid] = reinterpret_cast<const uint4*>(hcq)[tid];

    // wave shuffle reduction of tversky partials -> single float4 store
    unsigned pcu = pc;
#pragma unroll
    for (int off = 32; off > 0; off >>= 1) {
        tp += __shfl_down(tp, off);
        Ssum += __shfl_down(Ssum, off);
        pcu += __shfl_down(pcu, off);
    }
    const int lane = tid & 63, w = tid >> 6;
    if (lane == 0) { red[w * 3] = tp; red[w * 3 + 1] = Ssum; red[w * 3 + 2] = (float)pcu; }
    __syncthreads();
    if (tid == 0) {
        gtv[blockIdx.x] = make_float4(red[0] + red[3] + red[6] + red[9],
                                      red[1] + red[4] + red[7] + red[10],
                                      red[2] + red[5] + red[8] + red[11], 0.0f);
    }
}

// k2: full-chip reduction of the 64 partial hists per image.
// Block (img, slice) sums gpart[img*BPI + 0..63][slice*128 + t] -> ghist.
__global__ __launch_bounds__(K2_THREADS) void k2_reduce(
    const unsigned* __restrict__ gpart, unsigned long long* __restrict__ ghist) {
    const int t = threadIdx.x;
    const int img = blockIdx.x >> 3;
    const int sl = blockIdx.x & (SLICES - 1);
    const int bin = sl * K2_THREADS + t;

    const unsigned* basep = gpart + (size_t)img * BPI * BINS + bin;
    unsigned c = 0, q = 0;
#pragma unroll 8
    for (int blk = 0; blk < BPI; ++blk) {
        unsigned u = basep[(size_t)blk * BINS];   // coalesced across threads
        c += (u >> 16);
        q += (u & 0xffffu);
    }
    ghist[(size_t)img * BINS + bin] = ((unsigned long long)c << 32) | (unsigned long long)q;
}

// k3: per-image descending scan + tversky + deterministic fixed-point combine.
__global__ __launch_bounds__(K3_THREADS) void k3_lovasz(
    const unsigned long long* __restrict__ ghist, const float4* __restrict__ gtv,
    unsigned long long* __restrict__ gacc, float* __restrict__ out) {
    const int img = blockIdx.x;
    const int t = threadIdx.x;
    const int lane = t & 63, w = t >> 6;

    __shared__ float smx[4];
    __shared__ unsigned long long wt[8];   // double-buffered wave step-totals
    __shared__ double rd[4];

    // ---- 1) reduce tversky partials (64 per image; wave 0 handles them) ----
    float4 v = make_float4(0.f, 0.f, 0.f, 0.f);
    if (t < 64) v = gtv[img * BPI + t];
#pragma unroll
    for (int off = 32; off > 0; off >>= 1) {
        v.x += __shfl_down(v.x, off);
        v.y += __shfl_down(v.y, off);
        v.z += __shfl_down(v.z, off);
    }
    if (t == 0) { smx[0] = v.x; smx[1] = v.y; smx[2] = v.z; }

    // ---- 2) load summed hist; thread t owns bins b = j*256 + t ----
    unsigned long long own[POS_PER_T];
    const unsigned long long* hb = ghist + (size_t)img * BINS;
#pragma unroll
    for (int j = 0; j < POS_PER_T; ++j) own[j] = hb[j * K3_THREADS + t];
    __syncthreads();
    const float tpv = smx[0], Sv = smx[1];
    const long long p = (long long)(smx[2] + 0.5f);
    const long long n = (long long)PIMG - p;

    // ---- 3) descending-e scan: steps j = 3..0 (bin j*256+t; larger bin = larger e) ----
    unsigned long long runHigh = 0ull;  // totals of all bins above current step
    double lov = 0.0;
    const double wbin = 8.0 / (double)BINS;

    for (int j = POS_PER_T - 1; j >= 0; --j) {
        const unsigned long long val = own[j];
        // wave inclusive suffix sum: incl[t] = sum_{t'>=t in wave} val[t']
        unsigned long long incl = val;
#pragma unroll
        for (int off = 1; off < 64; off <<= 1) {
            unsigned long long o = __shfl_down(incl, off);
            if (lane + off < 64) incl += o;
        }
        const int buf = (j & 1) * 4;
        if (lane == 0) wt[buf + w] = incl;
        __syncthreads();
        unsigned long long higher = 0ull, stepTotal = 0ull;
#pragma unroll
        for (int w2 = 0; w2 < 4; ++w2) {
            unsigned long long tw = wt[buf + w2];
            stepTotal += tw;
            if (w2 > w) higher += tw;
        }
        const unsigned long long before = runHigh + higher + (incl - val);

        const long long g = (long long)(val >> 32);
        if (g) {
            const long long q = (long long)(val & 0xffffffffull);
            const long long N0 = (long long)(before >> 32);
            const long long C0 = (long long)(before & 0xffffffffull);
            const int bin = j * K3_THREADS + t;
            const double center = ((double)bin + 0.5) * wbin;
            const long long Ib = p - C0;        // intersection before
            const long long Ub = p + N0 - C0;   // union before
            const long long Ia = Ib - q;
            const long long Ua = Ub + g - q;
            if (n > 0) {
                double dJ;
                if (N0 == 0) {
                    // sum of grads over first bin telescopes to J_after
                    dJ = 1.0 - (double)Ia / (double)Ua;
                } else {
                    // J_after - J_before = (Ib*(g-q) + q*Ub) / (Ua*Ub)
                    const long long num = Ib * (g - q) + q * Ub;
                    dJ = (double)num / ((double)Ua * (double)Ub);
                }
                lov += center * dJ;
            } else {
                const double Jafter = 1.0 - (double)Ia / (double)Ua;
                lov += (double)g * center * Jafter;
            }
        }
        runHigh += stepTotal;
    }

    // ---- 4) reduce lov across block, combine, fixed-point atomic accumulate ----
#pragma unroll
    for (int off = 32; off > 0; off >>= 1) lov += __shfl_down(lov, off);
    if (lane == 0) rd[w] = lov;
    __syncthreads();
    if (t == 0) {
        const double lovt = rd[0] + rd[1] + rd[2] + rd[3];
        const float pf = (float)p;
        const float fn = pf - tpv;
        const float fp_ = Sv - tpv;
        const float tv = (tpv + 1e-6f) / (tpv + 0.3f * fn + 0.7f * fp_ + 1e-6f);
        float bse = 1.0f - tv;
        if (bse < 0.0f) bse = 0.0f;
        const double contrib = ((double)powf(bse, 1.33f) + 0.2 * lovt) / (double)NIMG;
        const long long fx = (long long)(contrib * FIXED_SCALE);
        atomicAdd(&gacc[0], (unsigned long long)fx);
        __threadfence();
        const unsigned long long done = atomicAdd(&gacc[1], 1ull);
        if (done == (unsigned long long)(NIMG - 1)) {
            const unsigned long long sum = atomicAdd(&gacc[0], 0ull);  // coherent read
            out[0] = (float)((double)(long long)sum / FIXED_SCALE);
        }
    }
}

extern "C" void kernel_launch(void* const* d_in, const int* in_sizes, int n_in,
                              void* d_out, int out_size, void* d_ws, size_t ws_size,
                              hipStream_t stream) {
    const float* logits = (const float*)d_in[0];
    const int* targets = (const int*)d_in[1];
    float* out = (float*)d_out;
    char* ws = (char*)d_ws;

    unsigned* gpart = (unsigned*)ws;
    float4* gtv = (float4*)(ws + OFF_GTV);
    unsigned long long* ghist = (unsigned long long*)(ws + OFF_GHIST);
    unsigned long long* gacc = (unsigned long long*)(ws + OFF_GACC);

    k1_hist<<<NIMG * BPI, K1_THREADS, 0, stream>>>(logits, targets, gpart, gtv, gacc);
    k2_reduce<<<NIMG * SLICES, K2_THREADS, 0, stream>>>(gpart, ghist);
    k3_lovasz<<<NIMG, K3_THREADS, 0, stream>>>(ghist, gtv, gacc, out);
}